// Round 6
// baseline (177.103 us; speedup 1.0000x reference)
//
#include <hip/hip_runtime.h>

// CPRPackedLinear: out(64x11008) = xperm[:, :1024] @ deq6(W_high) + xperm[:, 1024:] @ deq5(W_low) + bias
//
// R6: six schedules all served weights at ~2.4 TB/s effective (HBM-side 1.25 TB/s)
// while the harness's own 330MB fill streams at 6.8 TB/s -> the wall is the access
// PATTERN: 256-B requests at 44-KB stride (one 64-col strip per packed row) kill
// DRAM page efficiency. This version doubles the burst: 128-col tiles, each
// staging request = one GLOAD16 with lane-split sources (lanes 0-31 -> row 2p,
// lanes 32-63 -> row 2p+1), i.e. 2x512-B contiguous spans per request, landing as
// a contiguous 1-KB LDS pair. 3-buffer rotation, depth-2 counted vmcnt (never 0
// mid-loop), one s_barrier/step, 3 blocks/CU. Waves own disjoint 32-col strips.

#define NFEAT 11008
#define KTOT  4096

typedef _Float16 half8 __attribute__((ext_vector_type(8)));
typedef float    f32x4 __attribute__((ext_vector_type(4)));

#define GLOAD16(g, l) __builtin_amdgcn_global_load_lds(                         \
    (const __attribute__((address_space(1))) unsigned int*)(g),                 \
    (__attribute__((address_space(3))) unsigned int*)(l), 16, 0, 0)
#define WAITV(N) asm volatile("s_waitcnt vmcnt(" #N ")" ::: "memory")
#define FENCE()  asm volatile("" ::: "memory")

// ---------------- prep: x_perm -> fp16 in MFMA A-fragment layout ----------------
// xfrag flat idx = ((s*4 + mt)*64 + lane)*8 + j
//   holds x[m = mt*16 + (lane&15)][ col_indices[k = s*32 + (lane>>4)*8 + j] ]
__global__ __launch_bounds__(256) void prep_xfrag(const float* __restrict__ x,
                                                  const int* __restrict__ col,
                                                  _Float16* __restrict__ xfrag) {
    int idx = blockIdx.x * 256 + threadIdx.x;          // 0..262143
    int j  = idx & 7;
    int l  = (idx >> 3) & 63;
    int mt = (idx >> 9) & 3;
    int s  = idx >> 11;
    int k  = s * 32 + ((l >> 4) << 3) + j;
    int m  = mt * 16 + (l & 15);
    xfrag[idx] = (_Float16)x[m * KTOT + col[k]];
}

// ---------------- main GEMM ----------------
// grid = (86, 8): 128-col tiles x 512-k chunks (kc 0..1 = 6-bit, kc 2..7 = 5-bit).
// block = 256 = 4 waves; wave w owns cols [128*bx + 32w, +32), all 64 rows.
// Per 32-k step: stage 24 (6b) / 20 (5b) packed rows as 512-B-span pairs via
// lane-split GLOAD16; each lane dequants 2 col-octets straight into B-frags.
__global__ __launch_bounds__(256, 3) void gemm_kernel(const int* __restrict__ Wh,
                                                      const int* __restrict__ Wl,
                                                      const float* __restrict__ sh,
                                                      const float* __restrict__ sl,
                                                      const _Float16* __restrict__ xfrag,
                                                      float* __restrict__ dst,
                                                      int atomic_mode) {
    const int bx   = blockIdx.x;
    const int kc   = blockIdx.y;
    const int lane = threadIdx.x & 63;
    const int wave = threadIdx.x >> 6;                  // 0..3
    const int n0   = bx * 128;                          // global col base (ints == cols)
    const int o    = lane >> 4;                         // k-octet 0..3
    const int c0   = wave * 32 + (lane & 15);           // block-local col of nt=0
    // lane's global source offset within a row-pair GLOAD16:
    const int rsub = lane >> 5;                         // 0: row 2p, 1: row 2p+1
    const int coff = (lane & 31) * 4;                   // int offset in the 512-B span

    // Pair-packed W tiles: pair p at ints [p*264, p*264+256), 32-B pad -> row
    // stride 8 banks; octet groups land 24 banks apart (all exactly 2-way = free).
    __shared__ int Wb[3][12 * 264];                     // 3 bufs x 12.7 KB
    __shared__ __align__(16) _Float16 Ab[3][4][512];    // 3 bufs x 4 KB

    f32x4 acc[4][2];
#pragma unroll
    for (int i = 0; i < 4; ++i)
#pragma unroll
        for (int j = 0; j < 2; ++j) acc[i][j] = (f32x4){0.f, 0.f, 0.f, 0.f};

    if (kc < 2) {
        // ================= 6-bit region: k0 = 512*kc, 16 steps of 32-k =================
        const int k0    = kc * 512;
        const int rbase = 3 * (k0 >> 2);                // packed-row base of chunk
        float sc[4][2];                                  // scales: 4 groups x 2 nt
#pragma unroll
        for (int g = 0; g < 4; ++g)
#pragma unroll
            for (int nt = 0; nt < 2; ++nt)
                sc[g][nt] = sh[((k0 >> 7) + g) * NFEAT + n0 + c0 + nt * 16];

#define STAGE6(T, BUF) do {                                                     \
        const int _rb = rbase + (T) * 24;                                       \
        _Pragma("unroll")                                                       \
        for (int _i = 0; _i < 3; ++_i) {                                        \
            const int _p = 3 * wave + _i;                                       \
            GLOAD16(Wh + (size_t)(_rb + 2 * _p + rsub) * NFEAT + n0 + coff,     \
                    &Wb[BUF][_p * 264]);                                        \
        }                                                                       \
        GLOAD16(xfrag + ((size_t)((kc * 16 + (T)) * 4 + wave) * 64 + lane) * 8, \
                &Ab[BUF][wave][0]);                                             \
    } while (0)

        STAGE6(0, 0);
        STAGE6(1, 1);
#pragma unroll
        for (int t = 0; t < 16; ++t) {
            if (t < 15) { WAITV(4); } else { WAITV(0); }   // retire batch t, keep t+1 in flight
            __builtin_amdgcn_s_barrier();
            FENCE();
            if (t + 2 < 16) STAGE6(t + 2, (t + 2) % 3);
            const int bi = t % 3;
#pragma unroll
            for (int nt = 0; nt < 2; ++nt) {
                const int c = c0 + nt * 16;
                const int b0 = Wb[bi][(3 * o + 0) * 264 +   0 + c];
                const int b1 = Wb[bi][(3 * o + 0) * 264 + 128 + c];
                const int b2 = Wb[bi][(3 * o + 1) * 264 +   0 + c];
                const int b3 = Wb[bi][(3 * o + 1) * 264 + 128 + c];
                const int b4 = Wb[bi][(3 * o + 2) * 264 +   0 + c];
                const int b5 = Wb[bi][(3 * o + 2) * 264 + 128 + c];
                int v0 = b0 & 63;
                int v1 = ((b0 >> 6) & 3) | ((b1 & 15) << 2);
                int v2 = ((b1 >> 4) & 15) | ((b2 & 3) << 4);
                int v3 = (b2 >> 2) & 63;
                int v4 = b3 & 63;
                int v5 = ((b3 >> 6) & 3) | ((b4 & 15) << 2);
                int v6 = ((b4 >> 4) & 15) | ((b5 & 3) << 4);
                int v7 = (b5 >> 2) & 63;
                const float s = sc[t >> 2][nt], moff = -31.0f * s;
                half8 bf;
                bf[0] = (_Float16)fmaf((float)v0, s, moff);
                bf[1] = (_Float16)fmaf((float)v1, s, moff);
                bf[2] = (_Float16)fmaf((float)v2, s, moff);
                bf[3] = (_Float16)fmaf((float)v3, s, moff);
                bf[4] = (_Float16)fmaf((float)v4, s, moff);
                bf[5] = (_Float16)fmaf((float)v5, s, moff);
                bf[6] = (_Float16)fmaf((float)v6, s, moff);
                bf[7] = (_Float16)fmaf((float)v7, s, moff);
#pragma unroll
                for (int mt = 0; mt < 4; ++mt) {
                    half8 a = *(const half8*)&Ab[bi][mt][lane * 8];
                    acc[mt][nt] = __builtin_amdgcn_mfma_f32_16x16x32_f16(a, bf, acc[mt][nt], 0, 0, 0);
                }
            }
        }
#undef STAGE6
    } else {
        // ================= 5-bit region: kl0 = 512*(kc-2), 16 steps of 32-k =================
        const int kl0   = (kc - 2) * 512;
        const int rbase = 5 * (kl0 >> 3);
        float sc[4][2];
#pragma unroll
        for (int g = 0; g < 4; ++g)
#pragma unroll
            for (int nt = 0; nt < 2; ++nt)
                sc[g][nt] = sl[((kl0 >> 7) + g) * NFEAT + n0 + c0 + nt * 16];

        // 10 pairs/step: waves 0,1 stage 3 pairs; waves 2,3 stage 2 pairs.
        const int npair = (wave < 2) ? 3 : 2;
        const int pbase = (wave < 2) ? 3 * wave : 2 * wave + 2;

#define STAGE5(T, BUF) do {                                                     \
        const int _rb = rbase + (T) * 20;                                       \
        for (int _i = 0; _i < npair; ++_i) {                                    \
            const int _p = pbase + _i;                                          \
            GLOAD16(Wl + (size_t)(_rb + 2 * _p + rsub) * NFEAT + n0 + coff,     \
                    &Wb[BUF][_p * 264]);                                        \
        }                                                                       \
        GLOAD16(xfrag + ((size_t)((kc * 16 + (T)) * 4 + wave) * 64 + lane) * 8, \
                &Ab[BUF][wave][0]);                                             \
    } while (0)

        STAGE5(0, 0);
        STAGE5(1, 1);
#pragma unroll
        for (int t = 0; t < 16; ++t) {
            if (t < 15) {                                  // retire batch t only
                if (wave < 2) { WAITV(4); } else { WAITV(3); }
            } else { WAITV(0); }
            __builtin_amdgcn_s_barrier();
            FENCE();
            if (t + 2 < 16) STAGE5(t + 2, (t + 2) % 3);
            const int bi = t % 3;
#pragma unroll
            for (int nt = 0; nt < 2; ++nt) {
                const int c = c0 + nt * 16;
                // rows 5o..5o+4 -> pair (5o+j)>>1, sub (5o+j)&1
                const int r0i = 5 * o;
                const int b0 = Wb[bi][((r0i + 0) >> 1) * 264 + ((r0i + 0) & 1) * 128 + c];
                const int b1 = Wb[bi][((r0i + 1) >> 1) * 264 + ((r0i + 1) & 1) * 128 + c];
                const int b2 = Wb[bi][((r0i + 2) >> 1) * 264 + ((r0i + 2) & 1) * 128 + c];
                const int b3 = Wb[bi][((r0i + 3) >> 1) * 264 + ((r0i + 3) & 1) * 128 + c];
                const int b4 = Wb[bi][((r0i + 4) >> 1) * 264 + ((r0i + 4) & 1) * 128 + c];
                int v0 = b0 & 31;
                int v1 = ((b0 >> 5) & 7) | ((b1 & 3) << 3);
                int v2 = (b1 >> 2) & 31;
                int v3 = ((b1 >> 7) & 1) | ((b2 & 15) << 1);
                int v4 = ((b2 >> 4) & 15) | ((b3 & 1) << 4);
                int v5 = (b3 >> 1) & 31;
                int v6 = ((b3 >> 6) & 3) | ((b4 & 7) << 2);
                int v7 = (b4 >> 3) & 31;
                const float s = sc[t >> 2][nt], moff = -15.0f * s;
                half8 bf;
                bf[0] = (_Float16)fmaf((float)v0, s, moff);
                bf[1] = (_Float16)fmaf((float)v1, s, moff);
                bf[2] = (_Float16)fmaf((float)v2, s, moff);
                bf[3] = (_Float16)fmaf((float)v3, s, moff);
                bf[4] = (_Float16)fmaf((float)v4, s, moff);
                bf[5] = (_Float16)fmaf((float)v5, s, moff);
                bf[6] = (_Float16)fmaf((float)v6, s, moff);
                bf[7] = (_Float16)fmaf((float)v7, s, moff);
#pragma unroll
                for (int mt = 0; mt < 4; ++mt) {
                    half8 a = *(const half8*)&Ab[bi][mt][lane * 8];
                    acc[mt][nt] = __builtin_amdgcn_mfma_f32_16x16x32_f16(a, bf, acc[mt][nt], 0, 0, 0);
                }
            }
        }
#undef STAGE5
    }

    // ---- epilogue: waves own disjoint cols -> direct store ----
    // D row = mt*16 + (lane>>4)*4 + r, col = n0 + c0 + nt*16
    const int r0 = (lane >> 4) << 2;
    if (atomic_mode) {
#pragma unroll
        for (int mt = 0; mt < 4; ++mt)
#pragma unroll
            for (int nt = 0; nt < 2; ++nt)
#pragma unroll
                for (int r = 0; r < 4; ++r)
                    atomicAdd(&dst[(mt * 16 + r0 + r) * NFEAT + n0 + c0 + nt * 16], acc[mt][nt][r]);
    } else {
        float* base = dst + (size_t)kc * 64 * NFEAT;
#pragma unroll
        for (int mt = 0; mt < 4; ++mt)
#pragma unroll
            for (int nt = 0; nt < 2; ++nt)
#pragma unroll
                for (int r = 0; r < 4; ++r)
                    base[(mt * 16 + r0 + r) * NFEAT + n0 + c0 + nt * 16] = acc[mt][nt][r];
    }
}

// ---------------- reduce: out = bias + sum_kc partial[kc] ----------------
__global__ __launch_bounds__(256) void reduce_out(const float* __restrict__ part,
                                                  const float* __restrict__ bias,
                                                  float* __restrict__ out, int nc) {
    const int idx = blockIdx.x * 256 + threadIdx.x;    // 0..176127 (float4 units)
    const int f   = idx * 4;
    const int n   = f % NFEAT;                          // NFEAT % 4 == 0 -> same row
    f32x4 sum = *(const f32x4*)(bias + n);
    for (int c = 0; c < nc; ++c)
        sum += *(const f32x4*)(part + (size_t)c * 704512 + f);
    *(f32x4*)(out + f) = sum;
}

__global__ __launch_bounds__(256) void init_bias(const float* __restrict__ bias,
                                                 float* __restrict__ out) {
    const int idx = blockIdx.x * 256 + threadIdx.x;    // 0..704511
    out[idx] = bias[idx % NFEAT];
}

extern "C" void kernel_launch(void* const* d_in, const int* in_sizes, int n_in,
                              void* d_out, int out_size, void* d_ws, size_t ws_size,
                              hipStream_t stream) {
    const float* x    = (const float*)d_in[0];
    const int*   Wh   = (const int*)d_in[1];
    const int*   Wl   = (const int*)d_in[2];
    const float* sh   = (const float*)d_in[3];
    const float* sl   = (const float*)d_in[4];
    const int*   col  = (const int*)d_in[5];
    const float* bias = (const float*)d_in[6];
    float* out = (float*)d_out;

    _Float16* xfrag = (_Float16*)d_ws;                 // 512 KB
    const size_t xfrag_bytes = 64 * KTOT * sizeof(_Float16);
    const size_t part1 = 64ull * NFEAT * sizeof(float);         // 2.816 MB per chunk

    prep_xfrag<<<1024, 256, 0, stream>>>(x, col, xfrag);

    dim3 grid(86, 8);
    if (ws_size >= xfrag_bytes + 8 * part1) {
        float* part = (float*)((char*)d_ws + xfrag_bytes);
        gemm_kernel<<<grid, 256, 0, stream>>>(Wh, Wl, sh, sl, xfrag, part, 0);
        reduce_out<<<688, 256, 0, stream>>>(part, bias, out, 8);
    } else {
        init_bias<<<2752, 256, 0, stream>>>(bias, out);
        gemm_kernel<<<grid, 256, 0, stream>>>(Wh, Wl, sh, sl, xfrag, out, 1);
    }
}